// Round 5
// baseline (697.939 us; speedup 1.0000x reference)
//
#include <hip/hip_runtime.h>
#include <hip/hip_bf16.h>

// ISTA split-bf16 MFMA, round 5 = round 4 structure + round 3 numerics.
// C' = S · d^T (A = S register-resident, B = d from LDS) so the m89 C-layout
// (D[m=lg*4+q][n=l15], m = output column j, n = d-row) makes the epilogue a
// single b128 write per N-tile. d stored PACKED: u32 = bf16_hi | bf16_lo<<16,
// layout [row][k], XOR-swizzled byte ^= (row&7)<<4 (2-way worst-case bank
// aliasing = free, for both b128 reads and writes).
//
// R4 bug fixed here: kt=3's lo-correction products were dropped; S's ~30
// unit-magnitude eigenmodes accumulate that ~1e-3/iter injection linearly
// over 1000 iters -> absmax 1.078. Full 24-MFMA set (Sh*dh + Sh*dl + Sl*dh,
// all 4 K-tiles) restores R3's passing numerics (absmax 0.031).
// 3 independent accumulator chains keep MFMA dep depth at 4.
// One barrier per iter (read cur / write nxt double buffer).

#define ROWS     16
#define KPAD     128
#define N_DIM    100
#define M_DIM    70
#define NTHREADS 256

typedef __attribute__((ext_vector_type(8))) short short8;
typedef __attribute__((ext_vector_type(4))) float f32x4;
typedef __attribute__((ext_vector_type(4))) unsigned int u32x4;

static __device__ __forceinline__ unsigned short f2bf(float f) {
    unsigned u = __float_as_uint(f);
    u += 0x7FFF + ((u >> 16) & 1);          // RNE
    return (unsigned short)(u >> 16);
}
static __device__ __forceinline__ float bf2f(unsigned short b) {
    return __uint_as_float(((unsigned)b) << 16);
}

union v16 { u32x4 u; short8 s; };

__global__ __launch_bounds__(NTHREADS)
void ista_mfma3(const float* __restrict__ y,
                const float* __restrict__ S,
                const float* __restrict__ W,
                const float* __restrict__ thr,
                const int*   __restrict__ numIter,
                float* __restrict__ out)
{
    __shared__ __align__(16) unsigned int dp[2][ROWS * KPAD];  // packed hi|lo

    const int t    = threadIdx.x;
    const int wv   = t >> 6;        // wave 0..3 (2 N-tiles each)
    const int l    = t & 63;
    const int l15  = l & 15;
    const int lg   = l >> 4;
    const int row0 = blockIdx.x * ROWS;
    const float th  = thr[0];
    const int iters = numIter[0];
    const unsigned swz = (unsigned)((l15 & 7) << 4);

    // ---- one-time: S fragments as MFMA *A* operand (row = l15 = j-in-tile) ----
    short8 Sh[2][4], Sl[2][4];
    #pragma unroll
    for (int n2 = 0; n2 < 2; ++n2) {
        const int jg = (wv * 2 + n2) * 16 + l15;           // global output column
        #pragma unroll
        for (int kt = 0; kt < 4; ++kt) {
            #pragma unroll
            for (int i = 0; i < 8; ++i) {
                const int k = kt * 32 + lg * 8 + i;
                const float v = (jg < N_DIM && k < N_DIM) ? S[jg * N_DIM + k] : 0.f;
                const unsigned short hb = f2bf(v);
                Sh[n2][kt][i] = (short)hb;
                Sl[n2][kt][i] = (short)f2bf(v - bf2f(hb));
            }
        }
    }

    // ---- one-time: Wy in C' layout (lane: d-row = l15, j = tile + lg*4+q) ----
    f32x4 Wyr[2];
    #pragma unroll
    for (int n2 = 0; n2 < 2; ++n2) {
        #pragma unroll
        for (int q = 0; q < 4; ++q) {
            const int j = (wv * 2 + n2) * 16 + lg * 4 + q;
            float acc = 0.f;
            if (j < N_DIM) {
                const float* yr = y + (size_t)(row0 + l15) * M_DIM;
                const float* wr = W + (size_t)j * M_DIM;
                #pragma unroll 10
                for (int m = 0; m < M_DIM; ++m) acc = fmaf(yr[m], wr[m], acc);
            }
            Wyr[n2][q] = acc;
        }
    }

    // ---- zero buffer 0 ----
    for (int idx = t; idx < ROWS * KPAD; idx += NTHREADS) dp[0][idx] = 0u;
    __syncthreads();

    const unsigned* rb = dp[0];
    unsigned*       wb = dp[1];

    for (int it = 0; it < iters; ++it) {
        // ---- load + unpack d fragments (B operand: col = l15 = d-row) ----
        short8 Bh[4], Bl[4];
        #pragma unroll
        for (int kt = 0; kt < 4; ++kt) {
            const unsigned base = (unsigned)((l15 * KPAD + kt * 32 + lg * 8) * 4);
            const u32x4 pa = *(const u32x4*)((const char*)rb + ((base      ) ^ swz));
            const u32x4 pb = *(const u32x4*)((const char*)rb + ((base + 16u) ^ swz));
            v16 h, lo;
            h.u[0]  = __builtin_amdgcn_perm(pa[1], pa[0], 0x05040100u);
            h.u[1]  = __builtin_amdgcn_perm(pa[3], pa[2], 0x05040100u);
            h.u[2]  = __builtin_amdgcn_perm(pb[1], pb[0], 0x05040100u);
            h.u[3]  = __builtin_amdgcn_perm(pb[3], pb[2], 0x05040100u);
            lo.u[0] = __builtin_amdgcn_perm(pa[1], pa[0], 0x07060302u);
            lo.u[1] = __builtin_amdgcn_perm(pa[3], pa[2], 0x07060302u);
            lo.u[2] = __builtin_amdgcn_perm(pb[1], pb[0], 0x07060302u);
            lo.u[3] = __builtin_amdgcn_perm(pb[3], pb[2], 0x07060302u);
            Bh[kt] = h.s;
            Bl[kt] = lo.s;
        }

        // ---- 24 MFMAs, 3 independent chains per N-tile (dep depth = 4) ----
        f32x4 Chh[2] = { Wyr[0], Wyr[1] };
        f32x4 Chl[2] = { {0,0,0,0}, {0,0,0,0} };
        f32x4 Clh[2] = { {0,0,0,0}, {0,0,0,0} };
        #pragma unroll
        for (int kt = 0; kt < 4; ++kt) {
            #pragma unroll
            for (int n2 = 0; n2 < 2; ++n2)
                Chh[n2] = __builtin_amdgcn_mfma_f32_16x16x32_bf16(Sh[n2][kt], Bh[kt], Chh[n2], 0, 0, 0);
            #pragma unroll
            for (int n2 = 0; n2 < 2; ++n2)
                Chl[n2] = __builtin_amdgcn_mfma_f32_16x16x32_bf16(Sh[n2][kt], Bl[kt], Chl[n2], 0, 0, 0);
            #pragma unroll
            for (int n2 = 0; n2 < 2; ++n2)
                Clh[n2] = __builtin_amdgcn_mfma_f32_16x16x32_bf16(Sl[n2][kt], Bh[kt], Clh[n2], 0, 0, 0);
        }

        // ---- epilogue: sum chains, softthr, pack, ONE b128 write per tile ----
        #pragma unroll
        for (int n2 = 0; n2 < 2; ++n2) {
            u32x4 pk;
            #pragma unroll
            for (int q = 0; q < 4; ++q) {
                const float s = Chh[n2][q] + Chl[n2][q] + Clh[n2][q];
                float mag = fabsf(s) - th;
                mag = mag > 0.f ? mag : 0.f;
                const float r = (s >= 0.f) ? mag : -mag;
                const unsigned short hb = f2bf(r);
                const unsigned short lb = f2bf(r - bf2f(hb));
                pk[q] = (unsigned)hb | ((unsigned)lb << 16);
            }
            const unsigned boff =
                (unsigned)((l15 * KPAD + (wv * 2 + n2) * 16 + lg * 4) * 4) ^ swz;
            *(u32x4*)((char*)wb + boff) = pk;
        }

        __syncthreads();          // single barrier: next iter reads what we wrote
        const unsigned* tmp = rb; rb = wb; wb = (unsigned*)tmp;
    }

    // ---- output: unpack hi+lo, write global ----
    for (int idx = t; idx < ROWS * N_DIM; idx += NTHREADS) {
        const int r = idx / N_DIM;
        const int j = idx - r * N_DIM;
        const unsigned off = (unsigned)((r * KPAD + j) * 4) ^ (unsigned)((r & 7) << 4);
        const unsigned v = *(const unsigned*)((const char*)rb + off);
        out[(size_t)(row0 + r) * N_DIM + j] =
            bf2f((unsigned short)(v & 0xFFFFu)) + bf2f((unsigned short)(v >> 16));
    }
}

extern "C" void kernel_launch(void* const* d_in, const int* in_sizes, int n_in,
                              void* d_out, int out_size, void* d_ws, size_t ws_size,
                              hipStream_t stream) {
    const float* y       = (const float*)d_in[0];
    const float* S       = (const float*)d_in[1];
    const float* W       = (const float*)d_in[2];
    const float* thr     = (const float*)d_in[3];
    const int*   numIter = (const int*)d_in[4];
    float* out = (float*)d_out;

    const int Brows = in_sizes[0] / M_DIM;   // 4096
    const int nblk  = Brows / ROWS;          // 256 blocks = 1/CU
    ista_mfma3<<<nblk, NTHREADS, 0, stream>>>(y, S, W, thr, numIter, out);
}